// Round 1
// baseline (48113.181 us; speedup 1.0000x reference)
//
#include <hip/hip_runtime.h>
#include <stdint.h>
#include <limits.h>

// Problem constants (match reference)
#define T_STEPS 100
#define BSZ 512
#define HL 1024
#define HC 256
#define EMB 256
#define VOC 32000
#define NCHUNK 500           // VOC / 64
// JAX threefry variant: modern default (jax >= 0.4.30) is partitionable.
#define THREEFRY_PARTITIONABLE 1

// ---------------- threefry2x32 (JAX-exact) ----------------
__device__ __forceinline__ void threefry2x32(uint32_t k0, uint32_t k1,
                                             uint32_t x0, uint32_t x1,
                                             uint32_t& o0, uint32_t& o1) {
  uint32_t ks2 = k0 ^ k1 ^ 0x1BD11BDAu;
  x0 += k0; x1 += k1;
#define TF_R(x, r) (((x) << (r)) | ((x) >> (32 - (r))))
#define TF_RND(r) { x0 += x1; x1 = TF_R(x1, r); x1 ^= x0; }
  TF_RND(13) TF_RND(15) TF_RND(26) TF_RND(6)
  x0 += k1; x1 += ks2 + 1u;
  TF_RND(17) TF_RND(29) TF_RND(16) TF_RND(24)
  x0 += ks2; x1 += k0 + 2u;
  TF_RND(13) TF_RND(15) TF_RND(26) TF_RND(6)
  x0 += k0; x1 += k1 + 3u;
  TF_RND(17) TF_RND(29) TF_RND(16) TF_RND(24)
  x0 += k1; x1 += ks2 + 4u;
  TF_RND(13) TF_RND(15) TF_RND(26) TF_RND(6)
  x0 += ks2; x1 += k0 + 5u;
#undef TF_RND
#undef TF_R
  o0 = x0; o1 = x1;
}

// uniform(tiny,1) -> gumbel, matching jax._src.random exactly (f32 path)
__device__ __forceinline__ float gumbel_from_u32(uint32_t bits) {
  float f = __uint_as_float((bits >> 9) | 0x3f800000u) - 1.0f;
  f = fmaxf(f, 1.17549435e-38f);      // == f*(1-tiny)+tiny then max(tiny,.)
  return -logf(-logf(f));
}

__device__ __forceinline__ float read_temp(const int* p) {
  int v = *p;
  // harness stores python scalar as int32 (small int) or possibly f32 bits
  if (v >= -(1 << 24) && v <= (1 << 24)) return (float)v;
  return __int_as_float(v);
}

// ---------------- init: keys, token copy, H0 copy ----------------
__global__ __launch_bounds__(256) void k_init(const float* __restrict__ lang_h0,
                                              const int* __restrict__ inpt0,
                                              uint32_t* __restrict__ keys,
                                              int* __restrict__ cur_tok,
                                              float* __restrict__ H0) {
  int idx = blockIdx.x * 256 + threadIdx.x;
  if (idx < T_STEPS) {
    uint32_t o0, o1;
#if THREEFRY_PARTITIONABLE
    // split foldlike: keys[t] = threefry(key, (hi=0, lo=t))
    threefry2x32(0u, 1u, 0u, (uint32_t)idx, o0, o1);
    keys[2 * idx] = o0; keys[2 * idx + 1] = o1;
#else
    // original split: bits(i): i<100 -> tf(i, i+100).o0 ; i>=100 -> tf(i-100, i).o1
    {
      uint32_t a0, a1;
      threefry2x32(0u, 1u, (uint32_t)(2 * idx), (uint32_t)(2 * idx + 100), a0, a1);
      // careful: need bits(2t) and bits(2t+1) separately
    }
    // bits(j) for j = 2t, 2t+1
    for (int j = 2 * idx; j <= 2 * idx + 1; j++) {
      uint32_t b0_, b1_;
      if (j < 100) { threefry2x32(0u, 1u, (uint32_t)j, (uint32_t)(j + 100), b0_, b1_); keys[j + (j & 1 ? 0 : 0)] = b0_; keys[j] = b0_; }
      else { threefry2x32(0u, 1u, (uint32_t)(j - 100), (uint32_t)j, b0_, b1_); keys[j] = b1_; }
    }
#endif
  }
  if (idx < BSZ) cur_tok[idx] = inpt0[idx];
  if (idx < BSZ * HL) H0[idx] = lang_h0[idx];
}

// ---------------- x = [emb[tok], ctx] ----------------
__global__ __launch_bounds__(256) void k_build_x(const float* __restrict__ emb,
                                                 const float* __restrict__ ctx,
                                                 const int* __restrict__ tok,
                                                 float* __restrict__ xcat) {
  int idx = blockIdx.x * 256 + threadIdx.x;       // 512*512
  int b = idx >> 9, k = idx & 511;
  float v;
  if (k < EMB) v = emb[(size_t)tok[b] * EMB + k];
  else v = ctx[(size_t)b * HC + (k - EMB)];
  xcat[idx] = v;
}

// ---------------- generic fp32 GEMM: C[512 x N] = A[512 x K] @ W[N x K]^T + bias
__global__ __launch_bounds__(256) void k_gemm_bias(const float* __restrict__ A,
                                                   const float* __restrict__ W,
                                                   const float* __restrict__ bias,
                                                   float* __restrict__ C,
                                                   int N, int K) {
  __shared__ float As[64][33];
  __shared__ float Ws[64][33];
  int tid = threadIdx.x;
  int tv = tid & 15, tb = tid >> 4;
  int col0 = blockIdx.x * 64, row0 = blockIdx.y * 64;
  float acc[4][4] = {};
  for (int k0 = 0; k0 < K; k0 += 32) {
#pragma unroll
    for (int i = 0; i < 8; i++) {
      int idx = tid + i * 256;
      int r = idx >> 5, k = idx & 31;
      As[r][k] = A[(size_t)(row0 + r) * K + k0 + k];
      Ws[r][k] = W[(size_t)(col0 + r) * K + k0 + k];
    }
    __syncthreads();
#pragma unroll
    for (int kk = 0; kk < 32; kk++) {
      float a[4], w[4];
#pragma unroll
      for (int i = 0; i < 4; i++) a[i] = As[tb * 4 + i][kk];
#pragma unroll
      for (int j = 0; j < 4; j++) w[j] = Ws[tv * 4 + j][kk];
#pragma unroll
      for (int i = 0; i < 4; i++)
#pragma unroll
        for (int j = 0; j < 4; j++) acc[i][j] += a[i] * w[j];
    }
    __syncthreads();
  }
#pragma unroll
  for (int i = 0; i < 4; i++)
#pragma unroll
    for (int j = 0; j < 4; j++) {
      int col = col0 + tv * 4 + j;
      C[(size_t)(row0 + tb * 4 + i) * N + col] = acc[i][j] + (bias ? bias[col] : 0.0f);
    }
}

// ---------------- GRU pointwise ----------------
__global__ __launch_bounds__(256) void k_gru_pointwise(const float* __restrict__ GI,
                                                       const float* __restrict__ GH,
                                                       const float* __restrict__ Hin,
                                                       float* __restrict__ Hout) {
  int idx = blockIdx.x * 256 + threadIdx.x;       // 512*1024
  int b = idx >> 10, i = idx & 1023;
  const float* gi = GI + (size_t)b * 3 * HL;
  const float* gh = GH + (size_t)b * 3 * HL;
  float r = 1.0f / (1.0f + expf(-(gi[i] + gh[i])));
  float z = 1.0f / (1.0f + expf(-(gi[HL + i] + gh[HL + i])));
  float n = tanhf(gi[2 * HL + i] + r * gh[2 * HL + i]);
  Hout[idx] = (1.0f - z) * n + z * Hin[idx];
}

// ---------------- logits + gumbel + per-chunk argmax ----------------
// grid: (500 v-chunks of 64, 8 batch tiles of 64)
__global__ __launch_bounds__(256) void k_logits_sample(const float* __restrict__ dec,
                                                       const float* __restrict__ emb,
                                                       const uint32_t* __restrict__ keys,
                                                       int t,
                                                       const int* __restrict__ temp_ptr,
                                                       float* __restrict__ pval,
                                                       int* __restrict__ pidx) {
  __shared__ float As[64][33];
  __shared__ float Es[64][33];
  __shared__ float rv[64][16];
  __shared__ int ri[64][16];
  int tid = threadIdx.x;
  int tv = tid & 15, tb = tid >> 4;
  int c = blockIdx.x;
  int b0 = blockIdx.y * 64;
  int v0 = c * 64;
  float acc[4][4] = {};
  for (int k0 = 0; k0 < EMB; k0 += 32) {
#pragma unroll
    for (int i = 0; i < 8; i++) {
      int idx = tid + i * 256;
      int r = idx >> 5, k = idx & 31;
      As[r][k] = dec[(size_t)(b0 + r) * EMB + k0 + k];
      Es[r][k] = emb[(size_t)(v0 + r) * EMB + k0 + k];
    }
    __syncthreads();
#pragma unroll
    for (int kk = 0; kk < 32; kk++) {
      float a[4], w[4];
#pragma unroll
      for (int i = 0; i < 4; i++) a[i] = As[tb * 4 + i][kk];
#pragma unroll
      for (int j = 0; j < 4; j++) w[j] = Es[tv * 4 + j][kk];
#pragma unroll
      for (int i = 0; i < 4; i++)
#pragma unroll
        for (int j = 0; j < 4; j++) acc[i][j] += a[i] * w[j];
    }
    __syncthreads();
  }
  float temp = read_temp(temp_ptr);
  uint32_t kk0 = keys[2 * t], kk1 = keys[2 * t + 1];
  float best[4];
  int bidx[4];
#pragma unroll
  for (int i = 0; i < 4; i++) { best[i] = -3.402823466e38f; bidx[i] = 0; }
#pragma unroll
  for (int j = 0; j < 4; j++) {
    int v = v0 + tv * 4 + j;
#pragma unroll
    for (int i = 0; i < 4; i++) {
      int b = b0 + tb * 4 + i;
      uint32_t o0, o1;
#if THREEFRY_PARTITIONABLE
      uint32_t m = (uint32_t)(b * VOC + v);        // 64-bit linear idx, hi=0
      threefry2x32(kk0, kk1, 0u, m, o0, o1);
      float g = gumbel_from_u32(o0 ^ o1);
#else
      uint32_t m = (uint32_t)(b * VOC + v);
      const uint32_t NH = (uint32_t)(BSZ / 2) * VOC;
      uint32_t bits;
      if (m < NH) { threefry2x32(kk0, kk1, m, m + NH, o0, o1); bits = o0; }
      else { threefry2x32(kk0, kk1, m - NH, m, o0, o1); bits = o1; }
      float g = gumbel_from_u32(bits);
#endif
      float s = acc[i][j] / temp + g;
      if (s > best[i]) { best[i] = s; bidx[i] = v; }
    }
  }
#pragma unroll
  for (int i = 0; i < 4; i++) { rv[tb * 4 + i][tv] = best[i]; ri[tb * 4 + i][tv] = bidx[i]; }
  __syncthreads();
  if (tid < 64) {
    float bv = rv[tid][0];
    int bi = ri[tid][0];
    for (int m2 = 1; m2 < 16; m2++) {
      float v2 = rv[tid][m2]; int i2 = ri[tid][m2];
      if (v2 > bv || (v2 == bv && i2 < bi)) { bv = v2; bi = i2; }
    }
    int b = b0 + tid;
    pval[(size_t)b * NCHUNK + c] = bv;
    pidx[(size_t)b * NCHUNK + c] = bi;
  }
}

// ---------------- final argmax over chunks ----------------
__global__ __launch_bounds__(256) void k_argmax_final(const float* __restrict__ pval,
                                                      const int* __restrict__ pidx,
                                                      int* __restrict__ cur_tok,
                                                      float* __restrict__ outs_t) {
  __shared__ float sv[256];
  __shared__ int si[256];
  int b = blockIdx.x, tid = threadIdx.x;
  float bv = -3.402823466e38f;
  int bi = INT_MAX;
  for (int c = tid; c < NCHUNK; c += 256) {
    float v = pval[(size_t)b * NCHUNK + c];
    int i2 = pidx[(size_t)b * NCHUNK + c];
    if (v > bv || (v == bv && i2 < bi)) { bv = v; bi = i2; }
  }
  sv[tid] = bv; si[tid] = bi;
  __syncthreads();
  for (int s = 128; s > 0; s >>= 1) {
    if (tid < s) {
      float v = sv[tid + s]; int i2 = si[tid + s];
      if (v > sv[tid] || (v == sv[tid] && i2 < si[tid])) { sv[tid] = v; si[tid] = i2; }
    }
    __syncthreads();
  }
  if (tid == 0) { cur_tok[b] = si[0]; outs_t[b] = (float)si[0]; }
}

extern "C" void kernel_launch(void* const* d_in, const int* in_sizes, int n_in,
                              void* d_out, int out_size, void* d_ws, size_t ws_size,
                              hipStream_t stream) {
  const float* lang_h0 = (const float*)d_in[0];
  const float* ctx_h   = (const float*)d_in[1];
  const float* emb     = (const float*)d_in[2];
  const float* dec_W   = (const float*)d_in[3];
  const float* dec_b   = (const float*)d_in[4];
  const float* w_ih    = (const float*)d_in[5];
  const float* w_hh    = (const float*)d_in[6];
  const float* b_ih    = (const float*)d_in[7];
  const float* b_hh    = (const float*)d_in[8];
  const int*   inpt0   = (const int*)d_in[9];
  const int*   temp_p  = (const int*)d_in[10];
  // d_in[11] = max_words (constant 100, hard-coded)

  float* out = (float*)d_out;
  float* outs = out;                           // [100][512] token ids as f32
  float* Hbase = out + (size_t)T_STEPS * BSZ;  // [102][512][1024]

  uint8_t* ws = (uint8_t*)d_ws;
  uint32_t* keys = (uint32_t*)ws;                          // 200 u32
  int* cur_tok = (int*)(ws + 1024);                        // 512 int
  float* xcat = (float*)(ws + 8192);                       // 512*512
  float* GI = xcat + (size_t)BSZ * 512;                    // 512*3072
  float* GH = GI + (size_t)BSZ * 3 * HL;                   // 512*3072
  float* decb = GH + (size_t)BSZ * 3 * HL;                 // 512*256
  float* pval = decb + (size_t)BSZ * EMB;                  // 512*500
  int* pidx = (int*)(pval + (size_t)BSZ * NCHUNK);         // 512*500

  k_init<<<(BSZ * HL) / 256, 256, 0, stream>>>(lang_h0, inpt0, keys, cur_tok, Hbase);

  for (int t = 0; t <= T_STEPS; t++) {
    const float* Hin = Hbase + (size_t)t * BSZ * HL;
    float* Hout = Hbase + (size_t)(t + 1) * BSZ * HL;
    k_build_x<<<(BSZ * 512) / 256, 256, 0, stream>>>(emb, ctx_h, cur_tok, xcat);
    k_gemm_bias<<<dim3(48, 8), 256, 0, stream>>>(xcat, w_ih, b_ih, GI, 3 * HL, 512);
    k_gemm_bias<<<dim3(48, 8), 256, 0, stream>>>(Hin, w_hh, b_hh, GH, 3 * HL, HL);
    k_gru_pointwise<<<(BSZ * HL) / 256, 256, 0, stream>>>(GI, GH, Hin, Hout);
    if (t == T_STEPS) break;                   // extra writer step: no sampling
    k_gemm_bias<<<dim3(4, 8), 256, 0, stream>>>(Hout, dec_W, dec_b, decb, EMB, HL);
    k_logits_sample<<<dim3(NCHUNK, 8), 256, 0, stream>>>(decb, emb, keys, t, temp_p,
                                                         pval, pidx);
    k_argmax_final<<<BSZ, 256, 0, stream>>>(pval, pidx, cur_tok, outs + (size_t)t * BSZ);
  }
}

// Round 2
// 36437.463 us; speedup vs baseline: 1.3204x; 1.3204x over previous
//
#include <hip/hip_runtime.h>
#include <stdint.h>
#include <limits.h>

// Problem constants (match reference)
#define T_STEPS 100
#define BSZ 512
#define HL 1024
#define HC 256
#define EMB 256
#define VOC 32000
#define NCHUNK 500           // VOC / 64

// ---------------- threefry2x32 (JAX-exact, partitionable variant verified R1) ----------------
__device__ __forceinline__ void threefry2x32(uint32_t k0, uint32_t k1,
                                             uint32_t x0, uint32_t x1,
                                             uint32_t& o0, uint32_t& o1) {
  uint32_t ks2 = k0 ^ k1 ^ 0x1BD11BDAu;
  x0 += k0; x1 += k1;
#define TF_R(x, r) (((x) << (r)) | ((x) >> (32 - (r))))
#define TF_RND(r) { x0 += x1; x1 = TF_R(x1, r); x1 ^= x0; }
  TF_RND(13) TF_RND(15) TF_RND(26) TF_RND(6)
  x0 += k1; x1 += ks2 + 1u;
  TF_RND(17) TF_RND(29) TF_RND(16) TF_RND(24)
  x0 += ks2; x1 += k0 + 2u;
  TF_RND(13) TF_RND(15) TF_RND(26) TF_RND(6)
  x0 += k0; x1 += k1 + 3u;
  TF_RND(17) TF_RND(29) TF_RND(16) TF_RND(24)
  x0 += k1; x1 += ks2 + 4u;
  TF_RND(13) TF_RND(15) TF_RND(26) TF_RND(6)
  x0 += ks2; x1 += k0 + 5u;
#undef TF_RND
#undef TF_R
  o0 = x0; o1 = x1;
}

__device__ __forceinline__ float gumbel_from_u32(uint32_t bits) {
  float f = __uint_as_float((bits >> 9) | 0x3f800000u) - 1.0f;
  f = fmaxf(f, 1.17549435e-38f);
  return -logf(-logf(f));
}

__device__ __forceinline__ float read_temp(const int* p) {
  int v = *p;
  if (v >= -(1 << 24) && v <= (1 << 24)) return (float)v;
  return __int_as_float(v);
}

// ---------------- init: keys, token copy, H0 copy ----------------
__global__ __launch_bounds__(256) void k_init(const float* __restrict__ lang_h0,
                                              const int* __restrict__ inpt0,
                                              uint32_t* __restrict__ keys,
                                              int* __restrict__ cur_tok,
                                              float* __restrict__ H0) {
  int idx = blockIdx.x * 256 + threadIdx.x;
  if (idx < T_STEPS) {
    uint32_t o0, o1;
    threefry2x32(0u, 1u, 0u, (uint32_t)idx, o0, o1);
    keys[2 * idx] = o0; keys[2 * idx + 1] = o1;
  }
  if (idx < BSZ) cur_tok[idx] = inpt0[idx];
  if (idx < BSZ * HL) H0[idx] = lang_h0[idx];
}

// ---------------- fused GRU GEMMs: GI = [emb[tok],ctx] @ w_ih^T + b_ih
//                                   GH = Hin @ w_hh^T + b_hh
// grid (3072/64=48, 512/64=8), 256 threads. Transposed-LDS, b128 inner reads.
__global__ __launch_bounds__(256) void k_gru_gemm(const float* __restrict__ emb,
                                                  const float* __restrict__ ctx,
                                                  const int* __restrict__ tok,
                                                  const float* __restrict__ Hin,
                                                  const float* __restrict__ w_ih,
                                                  const float* __restrict__ w_hh,
                                                  const float* __restrict__ b_ih,
                                                  const float* __restrict__ b_hh,
                                                  float* __restrict__ GI,
                                                  float* __restrict__ GH) {
  __shared__ __align__(16) float Ax[32][68];
  __shared__ __align__(16) float Ah[32][68];
  __shared__ __align__(16) float Wi[32][68];
  __shared__ __align__(16) float Wh[32][68];
  int tid = threadIdx.x;
  int tv = tid & 15, tb = tid >> 4;
  int col0 = blockIdx.x * 64, row0 = blockIdx.y * 64;
  int sr = tid >> 3;            // 0..31
  int kq = (tid & 7) * 4;       // 0,4,...,28
  float accI[4][4] = {};
  float accH[4][4] = {};

  for (int k0 = 0; k0 < HL; k0 += 32) {
    // stage Hin and w_hh blocks (transposed into LDS)
#pragma unroll
    for (int i = 0; i < 2; i++) {
      int r = sr + 32 * i;
      float4 h4 = *(const float4*)&Hin[(size_t)(row0 + r) * HL + k0 + kq];
      Ah[kq + 0][r] = h4.x; Ah[kq + 1][r] = h4.y; Ah[kq + 2][r] = h4.z; Ah[kq + 3][r] = h4.w;
      float4 w4 = *(const float4*)&w_hh[(size_t)(col0 + r) * HL + k0 + kq];
      Wh[kq + 0][r] = w4.x; Wh[kq + 1][r] = w4.y; Wh[kq + 2][r] = w4.z; Wh[kq + 3][r] = w4.w;
    }
    if (k0 < 512) {
      // stage x = [emb[tok], ctx] and w_ih blocks
#pragma unroll
      for (int i = 0; i < 2; i++) {
        int r = sr + 32 * i;
        int k = k0 + kq;
        const float* src;
        if (k < EMB) src = emb + (size_t)tok[row0 + r] * EMB + k;
        else         src = ctx + (size_t)(row0 + r) * HC + (k - EMB);
        float4 x4 = *(const float4*)src;
        Ax[kq + 0][r] = x4.x; Ax[kq + 1][r] = x4.y; Ax[kq + 2][r] = x4.z; Ax[kq + 3][r] = x4.w;
        float4 w4 = *(const float4*)&w_ih[(size_t)(col0 + r) * 512 + k0 + kq];
        Wi[kq + 0][r] = w4.x; Wi[kq + 1][r] = w4.y; Wi[kq + 2][r] = w4.z; Wi[kq + 3][r] = w4.w;
      }
    }
    __syncthreads();
    if (k0 < 512) {
#pragma unroll
      for (int kk = 0; kk < 32; kk++) {
        float4 ah = *(float4*)&Ah[kk][tb * 4];
        float4 wh = *(float4*)&Wh[kk][tv * 4];
        float4 ax = *(float4*)&Ax[kk][tb * 4];
        float4 wi = *(float4*)&Wi[kk][tv * 4];
        float ahv[4] = {ah.x, ah.y, ah.z, ah.w};
        float whv[4] = {wh.x, wh.y, wh.z, wh.w};
        float axv[4] = {ax.x, ax.y, ax.z, ax.w};
        float wiv[4] = {wi.x, wi.y, wi.z, wi.w};
#pragma unroll
        for (int i = 0; i < 4; i++)
#pragma unroll
          for (int j = 0; j < 4; j++) {
            accH[i][j] += ahv[i] * whv[j];
            accI[i][j] += axv[i] * wiv[j];
          }
      }
    } else {
#pragma unroll
      for (int kk = 0; kk < 32; kk++) {
        float4 ah = *(float4*)&Ah[kk][tb * 4];
        float4 wh = *(float4*)&Wh[kk][tv * 4];
        float ahv[4] = {ah.x, ah.y, ah.z, ah.w};
        float whv[4] = {wh.x, wh.y, wh.z, wh.w};
#pragma unroll
        for (int i = 0; i < 4; i++)
#pragma unroll
          for (int j = 0; j < 4; j++) accH[i][j] += ahv[i] * whv[j];
      }
    }
    __syncthreads();
  }
  int col = col0 + tv * 4;
  float4 bi4 = *(const float4*)&b_ih[col];
  float4 bh4 = *(const float4*)&b_hh[col];
  float biv[4] = {bi4.x, bi4.y, bi4.z, bi4.w};
  float bhv[4] = {bh4.x, bh4.y, bh4.z, bh4.w};
#pragma unroll
  for (int i = 0; i < 4; i++) {
    int row = row0 + tb * 4 + i;
    float4 oi, oh;
    oi.x = accI[i][0] + biv[0]; oi.y = accI[i][1] + biv[1];
    oi.z = accI[i][2] + biv[2]; oi.w = accI[i][3] + biv[3];
    oh.x = accH[i][0] + bhv[0]; oh.y = accH[i][1] + bhv[1];
    oh.z = accH[i][2] + bhv[2]; oh.w = accH[i][3] + bhv[3];
    *(float4*)&GI[(size_t)row * 3072 + col] = oi;
    *(float4*)&GH[(size_t)row * 3072 + col] = oh;
  }
}

// ---------------- GRU pointwise (float4) ----------------
__global__ __launch_bounds__(256) void k_gru_pointwise(const float* __restrict__ GI,
                                                       const float* __restrict__ GH,
                                                       const float* __restrict__ Hin,
                                                       float* __restrict__ Hout) {
  int idx = blockIdx.x * 256 + threadIdx.x;   // over 512*1024/4
  int b = idx >> 8, ic = (idx & 255) * 4;
  const float* gi = GI + (size_t)b * 3072;
  const float* gh = GH + (size_t)b * 3072;
  float4 ir = *(const float4*)&gi[ic];
  float4 iz = *(const float4*)&gi[HL + ic];
  float4 in_ = *(const float4*)&gi[2 * HL + ic];
  float4 hr = *(const float4*)&gh[ic];
  float4 hz = *(const float4*)&gh[HL + ic];
  float4 hn = *(const float4*)&gh[2 * HL + ic];
  float4 h = *(const float4*)&Hin[(size_t)b * HL + ic];
  float4 o;
  float irv[4] = {ir.x, ir.y, ir.z, ir.w}, izv[4] = {iz.x, iz.y, iz.z, iz.w};
  float inv[4] = {in_.x, in_.y, in_.z, in_.w}, hrv[4] = {hr.x, hr.y, hr.z, hr.w};
  float hzv[4] = {hz.x, hz.y, hz.z, hz.w}, hnv[4] = {hn.x, hn.y, hn.z, hn.w};
  float hv[4] = {h.x, h.y, h.z, h.w}, ov[4];
#pragma unroll
  for (int j = 0; j < 4; j++) {
    float r = 1.0f / (1.0f + expf(-(irv[j] + hrv[j])));
    float z = 1.0f / (1.0f + expf(-(izv[j] + hzv[j])));
    float n = tanhf(inv[j] + r * hnv[j]);
    ov[j] = (1.0f - z) * n + z * hv[j];
  }
  o.x = ov[0]; o.y = ov[1]; o.z = ov[2]; o.w = ov[3];
  *(float4*)&Hout[(size_t)b * HL + ic] = o;
}

// ---------------- dec GEMM: decb[512x256] = H @ dec_W^T + dec_b
// grid (256/64=4, 512/32=16), 256 thr; TM=32, TN=64.
__global__ __launch_bounds__(256) void k_dec_gemm(const float* __restrict__ H,
                                                  const float* __restrict__ dec_W,
                                                  const float* __restrict__ dec_b,
                                                  float* __restrict__ decb) {
  __shared__ __align__(16) float As[32][36];
  __shared__ __align__(16) float Ws[32][68];
  int tid = threadIdx.x;
  int tv = tid & 15, tb = tid >> 4;     // tb: 0..15 -> rows tb*2..+1
  int col0 = blockIdx.x * 64, row0 = blockIdx.y * 32;
  int sr = tid >> 3;
  int kq = (tid & 7) * 4;
  float acc[2][4] = {};
  for (int k0 = 0; k0 < HL; k0 += 32) {
    {
      float4 a4 = *(const float4*)&H[(size_t)(row0 + sr) * HL + k0 + kq];
      As[kq + 0][sr] = a4.x; As[kq + 1][sr] = a4.y; As[kq + 2][sr] = a4.z; As[kq + 3][sr] = a4.w;
    }
#pragma unroll
    for (int i = 0; i < 2; i++) {
      int r = sr + 32 * i;
      float4 w4 = *(const float4*)&dec_W[(size_t)(col0 + r) * HL + k0 + kq];
      Ws[kq + 0][r] = w4.x; Ws[kq + 1][r] = w4.y; Ws[kq + 2][r] = w4.z; Ws[kq + 3][r] = w4.w;
    }
    __syncthreads();
#pragma unroll
    for (int kk = 0; kk < 32; kk++) {
      float a0 = As[kk][tb * 2], a1 = As[kk][tb * 2 + 1];
      float4 w = *(float4*)&Ws[kk][tv * 4];
      float wv[4] = {w.x, w.y, w.z, w.w};
#pragma unroll
      for (int j = 0; j < 4; j++) {
        acc[0][j] += a0 * wv[j];
        acc[1][j] += a1 * wv[j];
      }
    }
    __syncthreads();
  }
  int col = col0 + tv * 4;
  float4 b4 = *(const float4*)&dec_b[col];
  float bv[4] = {b4.x, b4.y, b4.z, b4.w};
#pragma unroll
  for (int i = 0; i < 2; i++) {
    float4 o;
    o.x = acc[i][0] + bv[0]; o.y = acc[i][1] + bv[1];
    o.z = acc[i][2] + bv[2]; o.w = acc[i][3] + bv[3];
    *(float4*)&decb[(size_t)(row0 + tb * 2 + i) * EMB + col] = o;
  }
}

// ---------------- logits + gumbel + per-chunk argmax ----------------
// grid (500 v-chunks of 64, 8 batch tiles of 64)
__global__ __launch_bounds__(256) void k_logits_sample(const float* __restrict__ dec,
                                                       const float* __restrict__ emb,
                                                       const uint32_t* __restrict__ keys,
                                                       int t,
                                                       const int* __restrict__ temp_ptr,
                                                       float* __restrict__ pval,
                                                       int* __restrict__ pidx) {
  __shared__ __align__(16) float As[32][68];
  __shared__ __align__(16) float Es[32][68];
  __shared__ float rv[64][16];
  __shared__ int ri[64][16];
  int tid = threadIdx.x;
  int tv = tid & 15, tb = tid >> 4;
  int c = blockIdx.x;
  int b0 = blockIdx.y * 64;
  int v0 = c * 64;
  int sr = tid >> 3;
  int kq = (tid & 7) * 4;
  float acc[4][4] = {};
  for (int k0 = 0; k0 < EMB; k0 += 32) {
#pragma unroll
    for (int i = 0; i < 2; i++) {
      int r = sr + 32 * i;
      float4 a4 = *(const float4*)&dec[(size_t)(b0 + r) * EMB + k0 + kq];
      As[kq + 0][r] = a4.x; As[kq + 1][r] = a4.y; As[kq + 2][r] = a4.z; As[kq + 3][r] = a4.w;
      float4 e4 = *(const float4*)&emb[(size_t)(v0 + r) * EMB + k0 + kq];
      Es[kq + 0][r] = e4.x; Es[kq + 1][r] = e4.y; Es[kq + 2][r] = e4.z; Es[kq + 3][r] = e4.w;
    }
    __syncthreads();
#pragma unroll
    for (int kk = 0; kk < 32; kk++) {
      float4 a = *(float4*)&As[kk][tb * 4];
      float4 e = *(float4*)&Es[kk][tv * 4];
      float av[4] = {a.x, a.y, a.z, a.w};
      float ev[4] = {e.x, e.y, e.z, e.w};
#pragma unroll
      for (int i = 0; i < 4; i++)
#pragma unroll
        for (int j = 0; j < 4; j++) acc[i][j] += av[i] * ev[j];
    }
    __syncthreads();
  }
  float temp = read_temp(temp_ptr);
  uint32_t kk0 = keys[2 * t], kk1 = keys[2 * t + 1];
  float best[4];
  int bidx[4];
#pragma unroll
  for (int i = 0; i < 4; i++) { best[i] = -3.402823466e38f; bidx[i] = 0; }
#pragma unroll
  for (int j = 0; j < 4; j++) {
    int v = v0 + tv * 4 + j;
#pragma unroll
    for (int i = 0; i < 4; i++) {
      int b = b0 + tb * 4 + i;
      uint32_t o0, o1;
      uint32_t m = (uint32_t)(b * VOC + v);    // < 2^24, hi word = 0
      threefry2x32(kk0, kk1, 0u, m, o0, o1);
      float g = gumbel_from_u32(o0 ^ o1);
      float s = acc[i][j] / temp + g;
      if (s > best[i]) { best[i] = s; bidx[i] = v; }
    }
  }
#pragma unroll
  for (int i = 0; i < 4; i++) { rv[tb * 4 + i][tv] = best[i]; ri[tb * 4 + i][tv] = bidx[i]; }
  __syncthreads();
  if (tid < 64) {
    float bv = rv[tid][0];
    int bi = ri[tid][0];
    for (int m2 = 1; m2 < 16; m2++) {
      float v2 = rv[tid][m2]; int i2 = ri[tid][m2];
      if (v2 > bv || (v2 == bv && i2 < bi)) { bv = v2; bi = i2; }
    }
    int b = b0 + tid;
    pval[(size_t)b * NCHUNK + c] = bv;
    pidx[(size_t)b * NCHUNK + c] = bi;
  }
}

// ---------------- final argmax over chunks ----------------
__global__ __launch_bounds__(256) void k_argmax_final(const float* __restrict__ pval,
                                                      const int* __restrict__ pidx,
                                                      int* __restrict__ cur_tok,
                                                      float* __restrict__ outs_t) {
  __shared__ float sv[256];
  __shared__ int si[256];
  int b = blockIdx.x, tid = threadIdx.x;
  float bv = -3.402823466e38f;
  int bi = INT_MAX;
  for (int c = tid; c < NCHUNK; c += 256) {
    float v = pval[(size_t)b * NCHUNK + c];
    int i2 = pidx[(size_t)b * NCHUNK + c];
    if (v > bv || (v == bv && i2 < bi)) { bv = v; bi = i2; }
  }
  sv[tid] = bv; si[tid] = bi;
  __syncthreads();
  for (int s = 128; s > 0; s >>= 1) {
    if (tid < s) {
      float v = sv[tid + s]; int i2 = si[tid + s];
      if (v > sv[tid] || (v == sv[tid] && i2 < si[tid])) { sv[tid] = v; si[tid] = i2; }
    }
    __syncthreads();
  }
  if (tid == 0) { cur_tok[b] = si[0]; outs_t[b] = (float)si[0]; }
}

extern "C" void kernel_launch(void* const* d_in, const int* in_sizes, int n_in,
                              void* d_out, int out_size, void* d_ws, size_t ws_size,
                              hipStream_t stream) {
  const float* lang_h0 = (const float*)d_in[0];
  const float* ctx_h   = (const float*)d_in[1];
  const float* emb     = (const float*)d_in[2];
  const float* dec_W   = (const float*)d_in[3];
  const float* dec_b   = (const float*)d_in[4];
  const float* w_ih    = (const float*)d_in[5];
  const float* w_hh    = (const float*)d_in[6];
  const float* b_ih    = (const float*)d_in[7];
  const float* b_hh    = (const float*)d_in[8];
  const int*   inpt0   = (const int*)d_in[9];
  const int*   temp_p  = (const int*)d_in[10];

  float* out = (float*)d_out;
  float* outs = out;                           // [100][512] token ids as f32
  float* Hbase = out + (size_t)T_STEPS * BSZ;  // [102][512][1024]

  uint8_t* ws = (uint8_t*)d_ws;
  uint32_t* keys = (uint32_t*)ws;                          // 200 u32
  int* cur_tok = (int*)(ws + 1024);                        // 512 int
  float* GI = (float*)(ws + 8192);                         // 512*3072
  float* GH = GI + (size_t)BSZ * 3 * HL;                   // 512*3072
  float* decb = GH + (size_t)BSZ * 3 * HL;                 // 512*256
  float* pval = decb + (size_t)BSZ * EMB;                  // 512*500
  int* pidx = (int*)(pval + (size_t)BSZ * NCHUNK);         // 512*500

  k_init<<<(BSZ * HL) / 256, 256, 0, stream>>>(lang_h0, inpt0, keys, cur_tok, Hbase);

  for (int t = 0; t <= T_STEPS; t++) {
    const float* Hin = Hbase + (size_t)t * BSZ * HL;
    float* Hout = Hbase + (size_t)(t + 1) * BSZ * HL;
    k_gru_gemm<<<dim3(48, 8), 256, 0, stream>>>(emb, ctx_h, cur_tok, Hin,
                                                w_ih, w_hh, b_ih, b_hh, GI, GH);
    k_gru_pointwise<<<(BSZ * HL / 4) / 256, 256, 0, stream>>>(GI, GH, Hin, Hout);
    if (t == T_STEPS) break;                   // extra writer step: no sampling
    k_dec_gemm<<<dim3(4, 16), 256, 0, stream>>>(Hout, dec_W, dec_b, decb);
    k_logits_sample<<<dim3(NCHUNK, 8), 256, 0, stream>>>(decb, emb, keys, t, temp_p,
                                                         pval, pidx);
    k_argmax_final<<<BSZ, 256, 0, stream>>>(pval, pidx, cur_tok, outs + (size_t)t * BSZ);
  }
}

// Round 4
// 30246.484 us; speedup vs baseline: 1.5907x; 1.2047x over previous
//
#include <hip/hip_runtime.h>
#include <stdint.h>
#include <limits.h>

// Problem constants (match reference)
#define T_STEPS 100
#define BSZ 512
#define HL 1024
#define HC 256
#define EMB 256
#define VOC 32000
#define NCHUNK 250           // VOC / 128

typedef __attribute__((ext_vector_type(8))) short short8;
typedef __attribute__((ext_vector_type(4))) float f32x4;
typedef __attribute__((ext_vector_type(4))) unsigned short u16x4;
#define MFMA16(a, b, c) __builtin_amdgcn_mfma_f32_16x16x32_bf16(a, b, c, 0, 0, 0)

// 6-term product of triple-split operands: residual ~2^-24 (fp32-class)
#define ACC6(acc, ah, am, al, bh, bm, bl) \
  { acc = MFMA16(ah, bh, acc); acc = MFMA16(ah, bm, acc); acc = MFMA16(am, bh, acc); \
    acc = MFMA16(ah, bl, acc); acc = MFMA16(am, bm, acc); acc = MFMA16(al, bh, acc); }

// ---------------- threefry2x32 (JAX-exact, partitionable variant verified R1) ----------------
__device__ __forceinline__ void threefry2x32(uint32_t k0, uint32_t k1,
                                             uint32_t x0, uint32_t x1,
                                             uint32_t& o0, uint32_t& o1) {
  uint32_t ks2 = k0 ^ k1 ^ 0x1BD11BDAu;
  x0 += k0; x1 += k1;
#define TF_R(x, r) (((x) << (r)) | ((x) >> (32 - (r))))
#define TF_RND(r) { x0 += x1; x1 = TF_R(x1, r); x1 ^= x0; }
  TF_RND(13) TF_RND(15) TF_RND(26) TF_RND(6)
  x0 += k1; x1 += ks2 + 1u;
  TF_RND(17) TF_RND(29) TF_RND(16) TF_RND(24)
  x0 += ks2; x1 += k0 + 2u;
  TF_RND(13) TF_RND(15) TF_RND(26) TF_RND(6)
  x0 += k0; x1 += k1 + 3u;
  TF_RND(17) TF_RND(29) TF_RND(16) TF_RND(24)
  x0 += k1; x1 += ks2 + 4u;
  TF_RND(13) TF_RND(15) TF_RND(26) TF_RND(6)
  x0 += ks2; x1 += k0 + 5u;
#undef TF_RND
#undef TF_R
  o0 = x0; o1 = x1;
}

__device__ __forceinline__ float gumbel_from_u32(uint32_t bits) {
  float f = __uint_as_float((bits >> 9) | 0x3f800000u) - 1.0f;
  f = fmaxf(f, 1.17549435e-38f);
  return -logf(-logf(f));
}

__device__ __forceinline__ float read_temp(const int* p) {
  int v = *p;
  if (v >= -(1 << 24) && v <= (1 << 24)) return (float)v;
  return __int_as_float(v);
}

__device__ __forceinline__ unsigned short f2bf(float x) {
  uint32_t u = __float_as_uint(x);
  u += 0x7fffu + ((u >> 16) & 1u);
  return (unsigned short)(u >> 16);
}
__device__ __forceinline__ float bf2f(unsigned short h) {
  return __uint_as_float(((uint32_t)h) << 16);
}
__device__ __forceinline__ void split3(float x, unsigned short& h,
                                       unsigned short& m, unsigned short& l) {
  h = f2bf(x);
  float r = x - bf2f(h);     // exact
  m = f2bf(r);
  r = r - bf2f(m);           // exact
  l = f2bf(r);
}

// ---------------- fp32 -> bf16 triple split (once per launch, for w_ih) ----------------
__global__ __launch_bounds__(256) void k_split3(const float* __restrict__ src,
                                                unsigned short* __restrict__ hi,
                                                unsigned short* __restrict__ mid,
                                                unsigned short* __restrict__ lo,
                                                int n4) {
  int i = blockIdx.x * 256 + threadIdx.x;
  if (i >= n4) return;
  float4 v = ((const float4*)src)[i];
  float vv[4] = {v.x, v.y, v.z, v.w};
  u16x4 h, m, l;
#pragma unroll
  for (int j = 0; j < 4; j++) {
    unsigned short a, b, c;
    split3(vv[j], a, b, c);
    h[j] = a; m[j] = b; l[j] = c;
  }
  ((u16x4*)hi)[i] = h;
  ((u16x4*)mid)[i] = m;
  ((u16x4*)lo)[i] = l;
}

// ---------------- init: keys, token copy, H0 copy ----------------
__global__ __launch_bounds__(256) void k_init(const float* __restrict__ lang_h0,
                                              const int* __restrict__ inpt0,
                                              uint32_t* __restrict__ keys,
                                              int* __restrict__ cur_tok,
                                              float* __restrict__ H0) {
  int idx = blockIdx.x * 256 + threadIdx.x;
  if (idx < T_STEPS) {
    uint32_t o0, o1;
    threefry2x32(0u, 1u, 0u, (uint32_t)idx, o0, o1);
    keys[2 * idx] = o0; keys[2 * idx + 1] = o1;
  }
  if (idx < BSZ) cur_tok[idx] = inpt0[idx];
  if (idx < BSZ * HL) H0[idx] = lang_h0[idx];
}

// ---------------- GI = [emb[tok],ctx] @ w_ih^T + b_ih, 6-term MFMA ----------------
// grid (3072/64=48, 512/64=8), 256 thr = 4 waves. Wave: 16 b x 64 n.
// A-side gathered fp32 and triple-split in-register; B from pre-split wih.
__global__ __launch_bounds__(256) void k_gi(
    const float* __restrict__ emb, const float* __restrict__ ctx,
    const int* __restrict__ tok,
    const unsigned short* __restrict__ wih_h, const unsigned short* __restrict__ wih_m,
    const unsigned short* __restrict__ wih_l,
    const float* __restrict__ b_ih, float* __restrict__ GI) {
  int tid = threadIdx.x;
  int wave = tid >> 6, lane = tid & 63;
  int ml = lane & 15, quad = lane >> 4;
  int n0 = blockIdx.x * 64;
  int bA = blockIdx.y * 64 + wave * 16 + ml;
  int myt = tok[bA];
  f32x4 acc[4];
#pragma unroll
  for (int tn = 0; tn < 4; tn++) acc[tn] = (f32x4){0.f, 0.f, 0.f, 0.f};

  for (int k0 = 0; k0 < 512; k0 += 32) {
    int k = k0 + quad * 8;
    const float* src = (k < 256) ? (emb + (size_t)myt * 256 + k)
                                 : (ctx + (size_t)bA * 256 + (k - 256));
    float4 x0 = *(const float4*)src;
    float4 x1 = *(const float4*)(src + 4);
    float xf[8] = {x0.x, x0.y, x0.z, x0.w, x1.x, x1.y, x1.z, x1.w};
    short8 ah, am_, al;
#pragma unroll
    for (int j = 0; j < 8; j++) {
      unsigned short a, b, c;
      split3(xf[j], a, b, c);
      ah[j] = (short)a; am_[j] = (short)b; al[j] = (short)c;
    }
#pragma unroll
    for (int tn = 0; tn < 4; tn++) {
      int n = n0 + tn * 16 + ml;
      size_t off = (size_t)n * 512 + k;
      short8 bh = *(const short8*)(wih_h + off);
      short8 bm = *(const short8*)(wih_m + off);
      short8 bl = *(const short8*)(wih_l + off);
      ACC6(acc[tn], ah, am_, al, bh, bm, bl);
    }
  }
  // C layout: col = lane&15 (n), row = quad*4+reg (b)
  int brow = blockIdx.y * 64 + wave * 16 + quad * 4;
#pragma unroll
  for (int tn = 0; tn < 4; tn++) {
    int n = n0 + tn * 16 + ml;
    float bias = b_ih[n];
#pragma unroll
    for (int reg = 0; reg < 4; reg++)
      GI[(size_t)(brow + reg) * 3072 + n] = acc[tn][reg] + bias;
  }
}

// ---------------- GRU: GH (fp32 vector) + GI add + pointwise, writes Hout ----------------
// grid (1024/32=32, 512/64=8), 128 thr. Block: 64 b x 32 i x 3 gates.
__global__ __launch_bounds__(128) void k_gru(const float* __restrict__ Hin,
                                             const float* __restrict__ w_hh,
                                             const float* __restrict__ b_hh,
                                             const float* __restrict__ GI,
                                             float* __restrict__ Hout) {
  __shared__ __align__(16) float Ah[32][68];
  __shared__ __align__(16) float Wr[32][34];
  __shared__ __align__(16) float Wz[32][34];
  __shared__ __align__(16) float Wn[32][34];
  int tid = threadIdx.x;
  int ti = tid & 15;
  int tb = tid >> 4;
  int b0 = blockIdx.y * 64, i0 = blockIdx.x * 32;
  int sr = tid >> 3;          // 0..15
  int kq = (tid & 7) * 4;
  float acc[3][8][2] = {};

  for (int k0 = 0; k0 < 1024; k0 += 32) {
#pragma unroll
    for (int i = 0; i < 4; i++) {
      int r = sr + 16 * i;
      float4 h4 = *(const float4*)&Hin[(size_t)(b0 + r) * 1024 + k0 + kq];
      Ah[kq + 0][r] = h4.x; Ah[kq + 1][r] = h4.y; Ah[kq + 2][r] = h4.z; Ah[kq + 3][r] = h4.w;
    }
#pragma unroll
    for (int g = 0; g < 3; g++) {
      float* Wg = (g == 0 ? &Wr[0][0] : g == 1 ? &Wz[0][0] : &Wn[0][0]);
      const float* src = w_hh + (size_t)(g * 1024 + i0) * 1024;
#pragma unroll
      for (int i = 0; i < 2; i++) {
        int r = sr + 16 * i;
        float4 w4 = *(const float4*)&src[(size_t)r * 1024 + k0 + kq];
        Wg[(kq + 0) * 34 + r] = w4.x; Wg[(kq + 1) * 34 + r] = w4.y;
        Wg[(kq + 2) * 34 + r] = w4.z; Wg[(kq + 3) * 34 + r] = w4.w;
      }
    }
    __syncthreads();
#pragma unroll
    for (int kk = 0; kk < 32; kk++) {
      float4 a0 = *(float4*)&Ah[kk][tb * 8];
      float4 a1 = *(float4*)&Ah[kk][tb * 8 + 4];
      float av[8] = {a0.x, a0.y, a0.z, a0.w, a1.x, a1.y, a1.z, a1.w};
      float2 wr2 = *(float2*)&Wr[kk][ti * 2];
      float2 wz2 = *(float2*)&Wz[kk][ti * 2];
      float2 wn2 = *(float2*)&Wn[kk][ti * 2];
      float wv0[2] = {wr2.x, wr2.y};
      float wv1[2] = {wz2.x, wz2.y};
      float wv2[2] = {wn2.x, wn2.y};
#pragma unroll
      for (int bb = 0; bb < 8; bb++)
#pragma unroll
        for (int j = 0; j < 2; j++) {
          acc[0][bb][j] += av[bb] * wv0[j];
          acc[1][bb][j] += av[bb] * wv1[j];
          acc[2][bb][j] += av[bb] * wv2[j];
        }
    }
    __syncthreads();
  }
  int i = i0 + ti * 2;
  float2 bhr = *(const float2*)&b_hh[i];
  float2 bhz = *(const float2*)&b_hh[1024 + i];
  float2 bhn = *(const float2*)&b_hh[2048 + i];
  float bhrv[2] = {bhr.x, bhr.y}, bhzv[2] = {bhz.x, bhz.y}, bhnv[2] = {bhn.x, bhn.y};
#pragma unroll
  for (int bb = 0; bb < 8; bb++) {
    int b = b0 + tb * 8 + bb;
    float2 gir = *(const float2*)&GI[(size_t)b * 3072 + i];
    float2 giz = *(const float2*)&GI[(size_t)b * 3072 + 1024 + i];
    float2 gin = *(const float2*)&GI[(size_t)b * 3072 + 2048 + i];
    float2 h2 = *(const float2*)&Hin[(size_t)b * 1024 + i];
    float girv[2] = {gir.x, gir.y}, gizv[2] = {giz.x, giz.y}, ginv[2] = {gin.x, gin.y};
    float hv[2] = {h2.x, h2.y}, ov[2];
#pragma unroll
    for (int j = 0; j < 2; j++) {
      float r = 1.0f / (1.0f + expf(-(girv[j] + acc[0][bb][j] + bhrv[j])));
      float z = 1.0f / (1.0f + expf(-(gizv[j] + acc[1][bb][j] + bhzv[j])));
      float n = tanhf(ginv[j] + r * (acc[2][bb][j] + bhnv[j]));
      ov[j] = (1.0f - z) * n + z * hv[j];
    }
    float2 o; o.x = ov[0]; o.y = ov[1];
    *(float2*)&Hout[(size_t)b * 1024 + i] = o;
  }
}

// ---------------- dec GEMM (fp32) + fused triple-split output ----------------
// grid (256/64=4, 512/16=32), 256 thr. Block: 16 b x 64 cols, K=1024.
__global__ __launch_bounds__(256) void k_dec(const float* __restrict__ H,
                                             const float* __restrict__ dec_W,
                                             const float* __restrict__ dec_b,
                                             unsigned short* __restrict__ dh,
                                             unsigned short* __restrict__ dm,
                                             unsigned short* __restrict__ dl) {
  __shared__ __align__(16) float As[32][20];
  __shared__ __align__(16) float Ws[32][68];
  int tid = threadIdx.x;
  int tb = tid >> 4;          // 0..15 = b row
  int tv = tid & 15;          // 4 cols: tv*4
  int col0 = blockIdx.x * 64, row0 = blockIdx.y * 16;
  int srw = tid >> 3;         // 0..31
  int kq = (tid & 7) * 4;
  float acc[4] = {};
  for (int k0 = 0; k0 < 1024; k0 += 32) {
    if (srw < 16) {           // As: 16 rows x 32 k
      float4 a4 = *(const float4*)&H[(size_t)(row0 + srw) * 1024 + k0 + kq];
      As[kq + 0][srw] = a4.x; As[kq + 1][srw] = a4.y; As[kq + 2][srw] = a4.z; As[kq + 3][srw] = a4.w;
    }
    // Ws: 64 rows x 32 k — rows srw and srw+32 (FIXED: R3 missed rows 32..47)
#pragma unroll
    for (int i = 0; i < 2; i++) {
      int r = srw + 32 * i;
      float4 w4 = *(const float4*)&dec_W[(size_t)(col0 + r) * 1024 + k0 + kq];
      Ws[kq + 0][r] = w4.x; Ws[kq + 1][r] = w4.y; Ws[kq + 2][r] = w4.z; Ws[kq + 3][r] = w4.w;
    }
    __syncthreads();
#pragma unroll
    for (int kk = 0; kk < 32; kk++) {
      float a = As[kk][tb];
      float4 w = *(float4*)&Ws[kk][tv * 4];
      float wv[4] = {w.x, w.y, w.z, w.w};
#pragma unroll
      for (int j = 0; j < 4; j++) acc[j] += a * wv[j];
    }
    __syncthreads();
  }
  int col = col0 + tv * 4;
  float4 b4 = *(const float4*)&dec_b[col];
  float bv[4] = {b4.x, b4.y, b4.z, b4.w};
  u16x4 h, m, l;
#pragma unroll
  for (int j = 0; j < 4; j++) {
    unsigned short a, b, c;
    split3(acc[j] + bv[j], a, b, c);
    h[j] = a; m[j] = b; l[j] = c;
  }
  size_t o = (size_t)(row0 + tb) * 256 + col;
  *(u16x4*)(dh + o) = h;
  *(u16x4*)(dm + o) = m;
  *(u16x4*)(dl + o) = l;
}

// ---------------- logits 6-term MFMA + gumbel + per-chunk argmax ----------------
// grid (250, 8), 128 thr = 2 waves. Block: 64 b x 128 v; wave: 32 b (2 m-tiles) x 128 v.
// B-side (emb) converted fp32 -> triple bf16 in LDS per k-tile (shared by both waves).
__global__ __launch_bounds__(128) void k_logits(const unsigned short* __restrict__ dh,
                                                const unsigned short* __restrict__ dm,
                                                const unsigned short* __restrict__ dl,
                                                const float* __restrict__ emb,
                                                const uint32_t* __restrict__ keys,
                                                int t,
                                                const int* __restrict__ temp_ptr,
                                                float* __restrict__ pval,
                                                int* __restrict__ pidx) {
  __shared__ __align__(16) unsigned short Eh[128 * 40];
  __shared__ __align__(16) unsigned short Em[128 * 40];
  __shared__ __align__(16) unsigned short El[128 * 40];
  int tid = threadIdx.x;
  int wave = tid >> 6, lane = tid & 63;
  int ml = lane & 15, quad = lane >> 4;
  int c = blockIdx.x;
  int v0 = c * 128;
  int b0 = blockIdx.y * 64;
  f32x4 acc[2][8];
#pragma unroll
  for (int mi = 0; mi < 2; mi++)
#pragma unroll
    for (int tv = 0; tv < 8; tv++) acc[mi][tv] = (f32x4){0.f, 0.f, 0.f, 0.f};

  for (int k0 = 0; k0 < 256; k0 += 32) {
    __syncthreads();
    // stage + split emb tile [128 v][32 k]
#pragma unroll
    for (int i = 0; i < 8; i++) {
      int idx4 = tid + i * 128;          // 0..1023 float4s
      int v = idx4 >> 3;
      int k4 = (idx4 & 7) * 4;
      float4 e4 = *(const float4*)&emb[(size_t)(v0 + v) * 256 + k0 + k4];
      float ev[4] = {e4.x, e4.y, e4.z, e4.w};
      u16x4 hh, mm, ll;
#pragma unroll
      for (int j = 0; j < 4; j++) {
        unsigned short a, b, cc;
        split3(ev[j], a, b, cc);
        hh[j] = a; mm[j] = b; ll[j] = cc;
      }
      *(u16x4*)&Eh[v * 40 + k4] = hh;
      *(u16x4*)&Em[v * 40 + k4] = mm;
      *(u16x4*)&El[v * 40 + k4] = ll;
    }
    __syncthreads();
    // A fragments (dec triple-split, global)
    short8 ah[2], am_[2], al[2];
#pragma unroll
    for (int mi = 0; mi < 2; mi++) {
      int brow = b0 + wave * 32 + mi * 16 + ml;
      size_t off = (size_t)brow * 256 + k0 + quad * 8;
      ah[mi] = *(const short8*)(dh + off);
      am_[mi] = *(const short8*)(dm + off);
      al[mi] = *(const short8*)(dl + off);
    }
#pragma unroll
    for (int tv = 0; tv < 8; tv++) {
      int lo = (tv * 16 + ml) * 40 + quad * 8;
      short8 bh = *(const short8*)&Eh[lo];
      short8 bm = *(const short8*)&Em[lo];
      short8 bl = *(const short8*)&El[lo];
#pragma unroll
      for (int mi = 0; mi < 2; mi++)
        ACC6(acc[mi][tv], ah[mi], am_[mi], al[mi], bh, bm, bl);
    }
  }
  float temp = read_temp(temp_ptr);
  uint32_t kk0 = keys[2 * t], kk1 = keys[2 * t + 1];
#pragma unroll
  for (int mi = 0; mi < 2; mi++) {
    float best[4];
    int bidx[4];
#pragma unroll
    for (int reg = 0; reg < 4; reg++) { best[reg] = -3.402823466e38f; bidx[reg] = INT_MAX; }
    // C layout: col (v) = lane&15, row (b) = quad*4+reg
#pragma unroll
    for (int tv = 0; tv < 8; tv++) {
      int v = v0 + tv * 16 + ml;
#pragma unroll
      for (int reg = 0; reg < 4; reg++) {
        int b = b0 + wave * 32 + mi * 16 + quad * 4 + reg;
        uint32_t o0, o1;
        threefry2x32(kk0, kk1, 0u, (uint32_t)(b * VOC + v), o0, o1);
        float s = acc[mi][tv][reg] / temp + gumbel_from_u32(o0 ^ o1);
        if (s > best[reg]) { best[reg] = s; bidx[reg] = v; }
      }
    }
#pragma unroll
    for (int off = 1; off < 16; off <<= 1) {
#pragma unroll
      for (int reg = 0; reg < 4; reg++) {
        float ov = __shfl_xor(best[reg], off, 64);
        int oi = __shfl_xor(bidx[reg], off, 64);
        if (ov > best[reg] || (ov == best[reg] && oi < bidx[reg])) {
          best[reg] = ov; bidx[reg] = oi;
        }
      }
    }
    if (ml == 0) {
#pragma unroll
      for (int reg = 0; reg < 4; reg++) {
        int b = b0 + wave * 32 + mi * 16 + quad * 4 + reg;
        pval[(size_t)b * NCHUNK + c] = best[reg];
        pidx[(size_t)b * NCHUNK + c] = bidx[reg];
      }
    }
  }
}

// ---------------- final argmax over chunks ----------------
__global__ __launch_bounds__(256) void k_argmax_final(const float* __restrict__ pval,
                                                      const int* __restrict__ pidx,
                                                      int* __restrict__ cur_tok,
                                                      float* __restrict__ outs_t) {
  __shared__ float sv[256];
  __shared__ int si[256];
  int b = blockIdx.x, tid = threadIdx.x;
  float bv = -3.402823466e38f;
  int bi = INT_MAX;
  for (int c = tid; c < NCHUNK; c += 256) {
    float v = pval[(size_t)b * NCHUNK + c];
    int i2 = pidx[(size_t)b * NCHUNK + c];
    if (v > bv || (v == bv && i2 < bi)) { bv = v; bi = i2; }
  }
  sv[tid] = bv; si[tid] = bi;
  __syncthreads();
  for (int s = 128; s > 0; s >>= 1) {
    if (tid < s) {
      float v = sv[tid + s]; int i2 = si[tid + s];
      if (v > sv[tid] || (v == sv[tid] && i2 < si[tid])) { sv[tid] = v; si[tid] = i2; }
    }
    __syncthreads();
  }
  if (tid == 0) { cur_tok[b] = si[0]; outs_t[b] = (float)si[0]; }
}

extern "C" void kernel_launch(void* const* d_in, const int* in_sizes, int n_in,
                              void* d_out, int out_size, void* d_ws, size_t ws_size,
                              hipStream_t stream) {
  const float* lang_h0 = (const float*)d_in[0];
  const float* ctx_h   = (const float*)d_in[1];
  const float* emb     = (const float*)d_in[2];
  const float* dec_W   = (const float*)d_in[3];
  const float* dec_b   = (const float*)d_in[4];
  const float* w_ih    = (const float*)d_in[5];
  const float* w_hh    = (const float*)d_in[6];
  const float* b_ih    = (const float*)d_in[7];
  const float* b_hh    = (const float*)d_in[8];
  const int*   inpt0   = (const int*)d_in[9];
  const int*   temp_p  = (const int*)d_in[10];

  float* out = (float*)d_out;
  float* outs = out;                           // [100][512] token ids as f32
  float* Hbase = out + (size_t)T_STEPS * BSZ;  // [102][512][1024]

  uint8_t* ws = (uint8_t*)d_ws;
  uint32_t* keys = (uint32_t*)ws;                               // 800 B
  int* cur_tok = (int*)(ws + 4096);                             // 2 KB
  unsigned short* dh = (unsigned short*)(ws + 8192);            // 512x256 bf16 x3
  unsigned short* dm = dh + (size_t)BSZ * EMB;
  unsigned short* dl = dm + (size_t)BSZ * EMB;
  float* pval = (float*)(dl + (size_t)BSZ * EMB);               // 512x250
  int* pidx = (int*)(pval + (size_t)BSZ * NCHUNK);
  float* GI = (float*)(pidx + (size_t)BSZ * NCHUNK);            // 512x3072 f32 (6 MB)
  unsigned short* wih_h = (unsigned short*)(GI + (size_t)BSZ * 3 * HL);  // 3072x512 x3
  unsigned short* wih_m = wih_h + (size_t)3 * HL * 512;
  unsigned short* wih_l = wih_m + (size_t)3 * HL * 512;
  // total ws use ~17 MB

  k_split3<<<(3 * HL * 512 / 4 + 255) / 256, 256, 0, stream>>>(w_ih, wih_h, wih_m, wih_l,
                                                               3 * HL * 512 / 4);
  k_init<<<(BSZ * HL) / 256, 256, 0, stream>>>(lang_h0, inpt0, keys, cur_tok, Hbase);

  for (int t = 0; t <= T_STEPS; t++) {
    const float* Hin = Hbase + (size_t)t * BSZ * HL;
    float* Hout = Hbase + (size_t)(t + 1) * BSZ * HL;
    k_gi<<<dim3(48, 8), 256, 0, stream>>>(emb, ctx_h, cur_tok,
                                          wih_h, wih_m, wih_l, b_ih, GI);
    k_gru<<<dim3(32, 8), 128, 0, stream>>>(Hin, w_hh, b_hh, GI, Hout);
    if (t == T_STEPS) break;                   // extra writer step: no sampling
    k_dec<<<dim3(4, 32), 256, 0, stream>>>(Hout, dec_W, dec_b, dh, dm, dl);
    k_logits<<<dim3(NCHUNK, 8), 128, 0, stream>>>(dh, dm, dl, emb, keys, t, temp_p,
                                                  pval, pidx);
    k_argmax_final<<<BSZ, 256, 0, stream>>>(pval, pidx, cur_tok, outs + (size_t)t * BSZ);
  }
}